// Round 1
// baseline (1414.777 us; speedup 1.0000x reference)
//
#include <hip/hip_runtime.h>

#define NTOK 64
#define DIM 256
#define NH 8
#define HD 32
#define BWIN 4096
#define TOPK 51

typedef _Float16 f16;
typedef _Float16 f16x8 __attribute__((ext_vector_type(8)));
typedef _Float16 f16x4 __attribute__((ext_vector_type(4)));
typedef float f32x4 __attribute__((ext_vector_type(4)));

#define MFMA(a, b, c) __builtin_amdgcn_mfma_f32_16x16x32_f16((a), (b), (c), 0, 0, 0)

// ---------------- prep: transpose weights to fp16, gather bias table ----------------
__global__ void prep_kernel(const float* __restrict__ Wqkv, const float* __restrict__ Wproj,
                            const float* __restrict__ bias_table, const int* __restrict__ rel_index,
                            f16* __restrict__ Wqt, f16* __restrict__ Wpt, float* __restrict__ biasp) {
    int tid = blockIdx.x * blockDim.x + threadIdx.x;
    const int nq = 768 * 256, np = 256 * 256, nb = NH * NTOK * NTOK;
    for (int i = tid; i < nq + np + nb; i += gridDim.x * blockDim.x) {
        if (i < nq) {
            int o = i >> 8, d = i & 255;
            Wqt[i] = (f16)Wqkv[d * 768 + o];
        } else if (i < nq + np) {
            int j = i - nq;
            int o = j >> 8, d = j & 255;
            Wpt[j] = (f16)Wproj[d * 256 + o];
        } else {
            int j = i - nq - np;
            int h = j >> 12;          // j / 4096
            int nm = j & 4095;
            biasp[j] = bias_table[rel_index[nm] * NH + h];
        }
    }
}

// ---------------- fused per-window kernel: 1 block (256 thr) per window ----------------
__global__ __launch_bounds__(256, 2)
void swin_kernel(const float* __restrict__ x, const float* __restrict__ var,
                 const float* __restrict__ b_qkv, const float* __restrict__ b_proj,
                 const f16* __restrict__ Wqt, const f16* __restrict__ Wpt,
                 const float* __restrict__ biasp, float* __restrict__ out) {
    __shared__ __align__(16) union {
        struct {
            f16 xv[64][264];                 // var(hi) in phase 1, x in phase 2. 33792 B
            union {
                float vs[64][65];            // var_self scores (phase 1)      16640 B
                f16 p[64][72];               // attn probs (phase 2)
            } s2;
            unsigned char mod[64][64];       // topk flag                       4096 B
            f16 qm[64][40];                  //                                 5120 B
            f16 km[64][40];                  //                                 5120 B
            f16 vT[32][72];                  // v transposed [d][m]             4608 B
            f16 oh[64][40];                  // per-head attn output            5120 B
        } a;
        struct {
            f16 pad[64 * 264];
            f16 lo[64][264];                 // var low part (phase 1 only)
        } b;
    } sm;

    const int tid = threadIdx.x;
    const int lane = tid & 63;
    const int w = tid >> 6;        // wave 0..3
    const int lc = lane & 15;      // col within 16x16 tile
    const int lq = lane >> 4;      // quad 0..3
    const int bwin = blockIdx.x;

    const float* varp = var + (size_t)bwin * NTOK * DIM;
    const float* xp = x + (size_t)bwin * NTOK * DIM;
    float* outp = out + (size_t)bwin * NTOK * DIM;

    // ---- phase 0: load var, split into fp16 hi + lo in LDS ----
    #pragma unroll
    for (int it = 0; it < 16; ++it) {
        int i = it * 256 + tid;            // float4 index, 4096 total
        int r = i >> 6, c4 = i & 63;
        float4 v4 = ((const float4*)varp)[i];
        f16 h0 = (f16)v4.x, h1 = (f16)v4.y, h2 = (f16)v4.z, h3 = (f16)v4.w;
        f16x4 hv = {h0, h1, h2, h3};
        f16x4 lv = {(f16)(v4.x - (float)h0), (f16)(v4.y - (float)h1),
                    (f16)(v4.z - (float)h2), (f16)(v4.w - (float)h3)};
        *(f16x4*)&sm.a.xv[r][c4 * 4] = hv;
        *(f16x4*)&sm.b.lo[r][c4 * 4] = lv;
    }
    __syncthreads();

    // ---- phase 1: var_self = var @ var^T (split-fp16, ~fp32 accuracy) ----
    f32x4 vacc[4];
    #pragma unroll
    for (int mt = 0; mt < 4; ++mt) vacc[mt] = (f32x4){0.f, 0.f, 0.f, 0.f};
    #pragma unroll
    for (int ks = 0; ks < 8; ++ks) {
        int k0 = ks * 32 + lq * 8;
        f16x8 ahi = *(const f16x8*)&sm.a.xv[w * 16 + lc][k0];
        f16x8 alo = *(const f16x8*)&sm.b.lo[w * 16 + lc][k0];
        #pragma unroll
        for (int mt = 0; mt < 4; ++mt) {
            f16x8 bhi = *(const f16x8*)&sm.a.xv[mt * 16 + lc][k0];
            f16x8 blo = *(const f16x8*)&sm.b.lo[mt * 16 + lc][k0];
            vacc[mt] = MFMA(ahi, bhi, vacc[mt]);
            vacc[mt] = MFMA(ahi, blo, vacc[mt]);
            vacc[mt] = MFMA(alo, bhi, vacc[mt]);
        }
    }
    __syncthreads();   // all lo reads done before vs (aliased) is written
    #pragma unroll
    for (int mt = 0; mt < 4; ++mt)
        #pragma unroll
        for (int r = 0; r < 4; ++r)
            sm.a.s2.vs[w * 16 + lq * 4 + r][mt * 16 + lc] = vacc[mt][r];
    __syncthreads();

    // ---- issue x loads (latency overlapped with topk) ----
    float4 xl[16];
    #pragma unroll
    for (int it = 0; it < 16; ++it) xl[it] = ((const float4*)xp)[it * 256 + tid];

    // ---- topk rank count: thread (row=tid>>2, quarter=tid&3) handles 16 cols ----
    {
        int n = tid >> 2, part = tid & 3;
        float vm[16];
        int cnt[16];
        #pragma unroll
        for (int i = 0; i < 16; ++i) { vm[i] = sm.a.s2.vs[n][part * 16 + i]; cnt[i] = 0; }
        for (int j = 0; j < 64; ++j) {
            float vj = sm.a.s2.vs[n][j];
            #pragma unroll
            for (int i = 0; i < 16; ++i) {
                int mi = part * 16 + i;
                cnt[i] += (int)((vj > vm[i]) | ((vj == vm[i]) & (j < mi)));
            }
        }
        #pragma unroll
        for (int i = 0; i < 16; ++i)
            sm.a.mod[n][part * 16 + i] = (cnt[i] < TOPK) ? 1 : 0;
    }

    // ---- store x (fp16) into xv ----
    #pragma unroll
    for (int it = 0; it < 16; ++it) {
        int i = it * 256 + tid;
        int r = i >> 6, c4 = i & 63;
        float4 v4 = xl[it];
        f16x4 hv = {(f16)v4.x, (f16)v4.y, (f16)v4.z, (f16)v4.w};
        *(f16x4*)&sm.a.xv[r][c4 * 4] = hv;
    }
    __syncthreads();

    // ---- phase 2: per-head attention, proj accumulated into registers ----
    f32x4 facc[4][4];
    #pragma unroll
    for (int rt = 0; rt < 4; ++rt)
        #pragma unroll
        for (int pt = 0; pt < 4; ++pt) facc[rt][pt] = (f32x4){0.f, 0.f, 0.f, 0.f};

    const float scale = 0.17677669529663687f;   // 32^-0.5

    for (int h = 0; h < NH; ++h) {
        // -- step A: q,k,v = x @ Wqkv slices (wave owns 16-row strip) --
        f32x4 qa[2], ka[2], va[2];
        #pragma unroll
        for (int ct = 0; ct < 2; ++ct) {
            qa[ct] = (f32x4){0.f, 0.f, 0.f, 0.f};
            ka[ct] = (f32x4){0.f, 0.f, 0.f, 0.f};
            va[ct] = (f32x4){0.f, 0.f, 0.f, 0.f};
        }
        #pragma unroll
        for (int ks = 0; ks < 8; ++ks) {
            int k0 = ks * 32 + lq * 8;
            f16x8 af = *(const f16x8*)&sm.a.xv[w * 16 + lc][k0];
            #pragma unroll
            for (int ct = 0; ct < 2; ++ct) {
                int oq = h * 32 + ct * 16 + lc;
                f16x8 bq = *(const f16x8*)&Wqt[(size_t)oq * 256 + k0];
                f16x8 bk = *(const f16x8*)&Wqt[(size_t)(256 + oq) * 256 + k0];
                f16x8 bv = *(const f16x8*)&Wqt[(size_t)(512 + oq) * 256 + k0];
                qa[ct] = MFMA(af, bq, qa[ct]);
                ka[ct] = MFMA(af, bk, ka[ct]);
                va[ct] = MFMA(af, bv, va[ct]);
            }
        }
        #pragma unroll
        for (int ct = 0; ct < 2; ++ct) {
            int oq = h * 32 + ct * 16 + lc;
            float bq = b_qkv[oq], bk = b_qkv[256 + oq], bv = b_qkv[512 + oq];
            #pragma unroll
            for (int r = 0; r < 4; ++r) {
                int row = w * 16 + lq * 4 + r;
                sm.a.qm[row][ct * 16 + lc] = (f16)(qa[ct][r] + bq);
                sm.a.km[row][ct * 16 + lc] = (f16)(ka[ct][r] + bk);
                sm.a.vT[ct * 16 + lc][row] = (f16)(va[ct][r] + bv);
            }
        }
        __syncthreads();

        // -- step B: dots = q k^T (K=32, one MFMA per tile) + softmax in-register --
        f32x4 dacc[4];
        {
            f16x8 qf = *(const f16x8*)&sm.a.qm[w * 16 + lc][lq * 8];
            #pragma unroll
            for (int mt = 0; mt < 4; ++mt) {
                f16x8 kf = *(const f16x8*)&sm.a.km[mt * 16 + lc][lq * 8];
                f32x4 zz = {0.f, 0.f, 0.f, 0.f};
                dacc[mt] = MFMA(qf, kf, zz);
            }
        }
        float pv[4][4], mx[4], lsum[4];
        #pragma unroll
        for (int r = 0; r < 4; ++r) mx[r] = -1e30f;
        #pragma unroll
        for (int mt = 0; mt < 4; ++mt)
            #pragma unroll
            for (int r = 0; r < 4; ++r) {
                int row = w * 16 + lq * 4 + r;
                int col = mt * 16 + lc;
                float modv = sm.a.mod[row][col] ? 1.0f : 1.2f;
                float bv = biasp[(h * 64 + row) * 64 + col];
                float t = dacc[mt][r] * scale * modv + bv;
                pv[mt][r] = t;
                mx[r] = fmaxf(mx[r], t);
            }
        #pragma unroll
        for (int r = 0; r < 4; ++r) {
            float m = mx[r];
            m = fmaxf(m, __shfl_xor(m, 1));
            m = fmaxf(m, __shfl_xor(m, 2));
            m = fmaxf(m, __shfl_xor(m, 4));
            m = fmaxf(m, __shfl_xor(m, 8));
            mx[r] = m;
            lsum[r] = 0.f;
        }
        #pragma unroll
        for (int mt = 0; mt < 4; ++mt)
            #pragma unroll
            for (int r = 0; r < 4; ++r) {
                float e = __expf(pv[mt][r] - mx[r]);
                pv[mt][r] = e;
                lsum[r] += e;
            }
        #pragma unroll
        for (int r = 0; r < 4; ++r) {
            float s = lsum[r];
            s += __shfl_xor(s, 1);
            s += __shfl_xor(s, 2);
            s += __shfl_xor(s, 4);
            s += __shfl_xor(s, 8);
            lsum[r] = s;
        }
        #pragma unroll
        for (int mt = 0; mt < 4; ++mt)
            #pragma unroll
            for (int r = 0; r < 4; ++r)
                sm.a.s2.p[w * 16 + lq * 4 + r][mt * 16 + lc] = (f16)pv[mt][r];
        __syncthreads();

        // -- step C: out_h = P @ V (v stored transposed -> contiguous B-frags) --
        f32x4 oacc[2];
        #pragma unroll
        for (int ct = 0; ct < 2; ++ct) oacc[ct] = (f32x4){0.f, 0.f, 0.f, 0.f};
        #pragma unroll
        for (int ks = 0; ks < 2; ++ks) {
            f16x8 pf = *(const f16x8*)&sm.a.s2.p[w * 16 + lc][ks * 32 + lq * 8];
            #pragma unroll
            for (int ct = 0; ct < 2; ++ct) {
                f16x8 vf = *(const f16x8*)&sm.a.vT[ct * 16 + lc][ks * 32 + lq * 8];
                oacc[ct] = MFMA(pf, vf, oacc[ct]);
            }
        }
        float rl[4];
        #pragma unroll
        for (int r = 0; r < 4; ++r) rl[r] = 1.0f / lsum[r];
        #pragma unroll
        for (int ct = 0; ct < 2; ++ct)
            #pragma unroll
            for (int r = 0; r < 4; ++r)
                sm.a.oh[w * 16 + lq * 4 + r][ct * 16 + lc] = (f16)(oacc[ct][r] * rl[r]);
        __syncthreads();

        // -- step D: final += out_h @ Wproj[h*32:(h+1)*32, wave's 64-col strip] --
        #pragma unroll
        for (int rt = 0; rt < 4; ++rt) {
            f16x8 af = *(const f16x8*)&sm.a.oh[rt * 16 + lc][lq * 8];
            #pragma unroll
            for (int pt = 0; pt < 4; ++pt) {
                f16x8 bf = *(const f16x8*)&Wpt[(size_t)(w * 64 + pt * 16 + lc) * 256 + h * 32 + lq * 8];
                facc[rt][pt] = MFMA(af, bf, facc[rt][pt]);
            }
        }
        __syncthreads();
    }

    // ---- epilogue: + b_proj, store fp32 ----
    #pragma unroll
    for (int pt = 0; pt < 4; ++pt) {
        int col = w * 64 + pt * 16 + lc;
        float bp = b_proj[col];
        #pragma unroll
        for (int rt = 0; rt < 4; ++rt)
            #pragma unroll
            for (int r = 0; r < 4; ++r) {
                int row = rt * 16 + lq * 4 + r;
                outp[row * 256 + col] = facc[rt][pt][r] + bp;
            }
    }
}

extern "C" void kernel_launch(void* const* d_in, const int* in_sizes, int n_in,
                              void* d_out, int out_size, void* d_ws, size_t ws_size,
                              hipStream_t stream) {
    const float* x          = (const float*)d_in[0];
    const float* var        = (const float*)d_in[1];
    const float* W_qkv      = (const float*)d_in[2];
    const float* b_qkv      = (const float*)d_in[3];
    const float* W_proj     = (const float*)d_in[4];
    const float* b_proj     = (const float*)d_in[5];
    const float* bias_table = (const float*)d_in[6];
    const int*   rel_index  = (const int*)d_in[7];

    f16*   Wqt   = (f16*)d_ws;                          // 768*256*2  = 393216 B
    f16*   Wpt   = (f16*)((char*)d_ws + 393216);        // 256*256*2  = 131072 B
    float* biasp = (float*)((char*)d_ws + 524288);      // 8*64*64*4  = 131072 B

    prep_kernel<<<288, 256, 0, stream>>>(W_qkv, W_proj, bias_table, rel_index, Wqt, Wpt, biasp);
    swin_kernel<<<BWIN, 256, 0, stream>>>(x, var, b_qkv, b_proj, Wqt, Wpt, biasp, (float*)d_out);
}